// Round 8
// baseline (192.842 us; speedup 1.0000x reference)
//
#include <hip/hip_runtime.h>

#define RANK 16
#define EMBED_DIM 128
#define CAP 16   // slot capacity; Poisson(3.2) P(deg>16) ~ 1e-8/node.
                 // Overflow list keeps arbitrary inputs correct.

typedef float floatx4 __attribute__((ext_vector_type(4)));  // clang-native:
// __builtin_nontemporal_store accepts this (HIP float4 is a class, rejected).

__device__ inline floatx4 shflx4(floatx4 v, int mask) {
    floatx4 r;
    r.x = __shfl_xor(v.x, mask);
    r.y = __shfl_xor(v.y, mask);
    r.z = __shfl_xor(v.z, mask);
    r.w = __shfl_xor(v.w, mask);
    return r;
}

// ---------------------------------------------------------------------------
// K1: one pass over edges, 2 edges/thread (16B vector loads, 1250 blocks ->
// ~5 blocks/CU TLP to hide atomic+scattered-store latency). Per-block dtype
// detect (odd 32-bit words of int64 layout are high halves of node ids <
// 2^31 -> all zero; int32 layout -> random ids, surely nonzero among 256
// samples). Then:
//   pos = atomicAdd(cnt[dst]); pos < CAP ? slots[dst*CAP+pos] = src
//                                        : append (src,dst) to overflow list.
// ---------------------------------------------------------------------------
__global__ __launch_bounds__(256) void fill_slots(
        const int* __restrict__ eiw,   // edge_index as 32-bit words
        int* __restrict__ cnt,         // [N], pre-zeroed
        int* __restrict__ ovfcnt,      // [1], pre-zeroed
        int* __restrict__ slots,       // [N*CAP]
        int* __restrict__ ovf,         // [2*E]
        int E, int nwords) {
    __shared__ int iflag;
    if (threadIdx.x == 0) iflag = 0;
    __syncthreads();
    {
        int w = 2 * threadIdx.x + 1;
        unsigned int v = (w < nwords) ? ((const unsigned int*)eiw)[w] : 0u;
        if (v) atomicOr(&iflag, 1);            // LDS atomic
    }
    __syncthreads();
    const bool is32 = (iflag != 0);

    const int base = (blockIdx.x * 256 + threadIdx.x) * 2;
    if (base >= E) return;

    int srcs[2], dsts[2];
    int ne;
    if ((E & 1) == 0 && base + 1 < E) {        // vector path (aligned: E even)
        ne = 2;
        if (is32) {                            // int32 layout: int2 loads
            int2 s = *(const int2*)(eiw + base);
            int2 d = *(const int2*)(eiw + E + base);
            srcs[0] = s.x; srcs[1] = s.y;
            dsts[0] = d.x; dsts[1] = d.y;
        } else {                               // int64 layout: int4, low words
            int4 sv = *(const int4*)(eiw + 2 * base);
            int4 dv = *(const int4*)(eiw + 2 * (E + base));
            srcs[0] = sv.x; srcs[1] = sv.z;
            dsts[0] = dv.x; dsts[1] = dv.z;
        }
    } else {                                   // scalar tail / odd shapes
        ne = 0;
        for (int e = base; e < E && e < base + 2; ++e, ++ne) {
            srcs[ne] = is32 ? eiw[e] : eiw[2 * e];
            dsts[ne] = is32 ? eiw[E + e] : eiw[2 * (E + e)];
        }
    }

#pragma unroll
    for (int j = 0; j < 2; ++j) {
        if (j >= ne) break;
        int dst = dsts[j];
        int pos = atomicAdd(&cnt[dst], 1);
        if (pos < CAP) {
            slots[(size_t)dst * CAP + pos] = srcs[j];
        } else {                               // essentially never
            int o = atomicAdd(ovfcnt, 1);
            ovf[2 * o]     = srcs[j];
            ovf[2 * o + 1] = dst;
        }
    }
}

// ---------------------------------------------------------------------------
// K2: fused atomic-free gather + projection. 256 threads, 64 nodes per block.
// Phase A: group g (16 lanes) owns node nd. Lane l covers edge-slot (l>>2)
//          and rank-quad (l&3): ONE global_load_dwordx4 per 4 edges per
//          group, 8-edge unroll -> 2 loads in flight. Partials combined by 2
//          shfl_xor rounds. Deterministic.
// Phase B: k-OUTER loop nest: each thread keeps 8 float4 accumulators in
//          registers and reads Vs4[k*32+q] ONCE per k (was once per k per
//          node = 8x). LDS traffic/thread: 2560B -> 768B; LDS instrs
//          256 -> 144. accs reads are wave-broadcast b32 (free of
//          conflicts). Nontemporal stores keep the 102 MB output stream
//          from evicting L2/L3-resident U and slots.
// Overflow fallback (deg > CAP) scans the tiny global list: correct for
// arbitrary inputs, never taken on random graphs.
// ---------------------------------------------------------------------------
__global__ __launch_bounds__(256) void gather_project(
        const float* __restrict__ U,
        const float* __restrict__ V,
        const int* __restrict__ cnt,
        const int* __restrict__ slots,
        const int* __restrict__ ovfcnt,
        const int* __restrict__ ovf,
        float* __restrict__ out, int N) {
    __shared__ float4  Vs4[RANK * EMBED_DIM / 4];  // 8 KB
    __shared__ floatx4 accs4[64][4];               // 4 KB
    __shared__ float   sinv[64];
    __shared__ int     scnt[64];
    __shared__ int4    sslot4[64 * CAP / 4];       // 4 KB, flat/linear

    const int t = threadIdx.x;
    const float4* V4 = (const float4*)V;
    Vs4[t]       = V4[t];
    Vs4[t + 256] = V4[t + 256];

    const int n0 = blockIdx.x * 64;

    if (t < 64) {
        int n = n0 + t;
        int c = (n < N) ? cnt[n] : 0;
        scnt[t] = c;
        sinv[t] = 1.0f / fmaxf((float)c, 1.0f);
    }
    {   // 64 nodes x 16 ints = 256 int4, linear ds_write_b128
        const int4* g4 = (const int4*)(slots + (size_t)n0 * CAP);
        if (n0 + (t >> 2) < N) sslot4[t] = g4[t];
    }
    __syncthreads();

    const int* sslot = (const int*)sslot4;
    const int g    = t >> 4;   // node group 0..15
    const int l    = t & 15;   // lane in group
    const int es   = l >> 2;   // edge slot 0..3
    const int quad = l & 3;    // rank quad 0..3

#pragma unroll
    for (int half = 0; half < 4; ++half) {
        int nd = half * 16 + g;
        int n = n0 + nd;
        int deg = scnt[nd];
        int k = deg < CAP ? deg : CAP;
        const int* sl = sslot + nd * CAP;
        floatx4 a = (floatx4)0.f;
        for (int e = 0; e < k; e += 8) {
            // e < k inside loop => k >= 1 => clamped index valid; poison
            // slots beyond deg are never dereferenced.
            int e0 = e + es;
            int e1 = e + 4 + es;
            int i0 = e0 < k ? e0 : k - 1;
            int i1 = e1 < k ? e1 : k - 1;
            int s0 = sl[i0];
            int s1 = sl[i1];
            floatx4 u0 = *(const floatx4*)(U + (size_t)s0 * RANK + 4 * quad);
            floatx4 u1 = *(const floatx4*)(U + (size_t)s1 * RANK + 4 * quad);
            if (e0 < k) a += u0;
            if (e1 < k) a += u1;
        }
        // combine the 4 edge-slot partials (masks stay inside the 16-lane group)
        a += shflx4(a, 4);
        a += shflx4(a, 8);
        if (l < 4) {                            // lane l holds rank-quad l
            if (deg > CAP) {                    // correctness fallback
                int m = *ovfcnt;
                for (int i = 0; i < m; ++i)
                    if (ovf[2 * i + 1] == n)
                        a += *(const floatx4*)(U + (size_t)ovf[2 * i] * RANK + 4 * l);
            }
            accs4[nd][l] = a;
        }
    }
    __syncthreads();

    const float* accsf = (const float*)accs4;
    const int q = t & 31;   // float4 column
    const int w = t >> 5;   // node octet: nodes w*8 .. w*8+7

    floatx4 o[8];
#pragma unroll
    for (int r = 0; r < 8; ++r) o[r] = (floatx4)0.f;

#pragma unroll
    for (int k = 0; k < RANK; ++k) {
        float4 v = Vs4[k * 32 + q];             // ONE b128 per k (was 8)
#pragma unroll
        for (int r = 0; r < 8; ++r) {
            float a = accsf[(w * 8 + r) * 16 + k];  // wave-broadcast b32
            o[r].x = fmaf(a, v.x, o[r].x);
            o[r].y = fmaf(a, v.y, o[r].y);
            o[r].z = fmaf(a, v.z, o[r].z);
            o[r].w = fmaf(a, v.w, o[r].w);
        }
    }

#pragma unroll
    for (int r = 0; r < 8; ++r) {
        int nd = w * 8 + r;
        int n = n0 + nd;
        if (n < N) {
            floatx4 oo = o[r] * sinv[nd];
            __builtin_nontemporal_store(
                oo, (floatx4*)out + (size_t)n * (EMBED_DIM / 4) + q);
        }
    }
}

extern "C" void kernel_launch(void* const* d_in, const int* in_sizes, int n_in,
                              void* d_out, int out_size, void* d_ws, size_t ws_size,
                              hipStream_t stream) {
    const float* U = (const float*)d_in[0];
    const float* V = (const float*)d_in[1];
    const int* EI = (const int*)d_in[2];
    float* out = (float*)d_out;

    const int N = in_sizes[0] / RANK;   // 200000
    const int E = in_sizes[2] / 2;      // 640000
    const int nwords = in_sizes[2];     // >= word count under both layouts

    // workspace (int32): cnt[N] | ovfcnt[1] | pad | slots[N*CAP] | ovf[2E]
    int* wsI = (int*)d_ws;
    int* cnt = wsI;
    int* ovfcnt = wsI + N;
    const int slots_off = (N + 1 + 15) & ~15;   // 16B-align slots for int4
    int* slots = wsI + slots_off;
    int* ovf = slots + (size_t)N * CAP;

    // zero cnt + ovfcnt only (0.8 MB)
    (void)hipMemsetAsync(d_ws, 0, (size_t)(N + 1) * sizeof(int), stream);

    fill_slots<<<(E / 2 + 255) / 256, 256, 0, stream>>>(
        EI, cnt, ovfcnt, slots, ovf, E, nwords);

    gather_project<<<(N + 63) / 64, 256, 0, stream>>>(
        U, V, cnt, slots, ovfcnt, ovf, out, N);
}

// Round 9
// 181.100 us; speedup vs baseline: 1.0648x; 1.0648x over previous
//
#include <hip/hip_runtime.h>

#define RANK 16
#define EMBED_DIM 128
#define CAP 16   // slot capacity; Poisson(3.2) P(deg>16) ~ 1e-8/node.
                 // Overflow list keeps arbitrary inputs correct.

typedef float floatx4 __attribute__((ext_vector_type(4)));  // clang-native:
// __builtin_nontemporal_store accepts this (HIP float4 is a class, rejected).

__device__ inline floatx4 shflx4(floatx4 v, int mask) {
    floatx4 r;
    r.x = __shfl_xor(v.x, mask);
    r.y = __shfl_xor(v.y, mask);
    r.z = __shfl_xor(v.z, mask);
    r.w = __shfl_xor(v.w, mask);
    return r;
}

// ---------------------------------------------------------------------------
// K1: one pass over edges, 2 edges/thread (16B vector loads, 1250 blocks ->
// ~5 blocks/CU TLP to hide atomic+scattered-store latency). Per-block dtype
// detect (odd 32-bit words of int64 layout are high halves of node ids <
// 2^31 -> all zero; int32 layout -> random ids, surely nonzero among 256
// samples). Then:
//   pos = atomicAdd(cnt[dst]); pos < CAP ? slots[dst*CAP+pos] = src
//                                        : append (src,dst) to overflow list.
// ---------------------------------------------------------------------------
__global__ __launch_bounds__(256) void fill_slots(
        const int* __restrict__ eiw,   // edge_index as 32-bit words
        int* __restrict__ cnt,         // [N], pre-zeroed
        int* __restrict__ ovfcnt,      // [1], pre-zeroed
        int* __restrict__ slots,       // [N*CAP]
        int* __restrict__ ovf,         // [2*E]
        int E, int nwords) {
    __shared__ int iflag;
    if (threadIdx.x == 0) iflag = 0;
    __syncthreads();
    {
        int w = 2 * threadIdx.x + 1;
        unsigned int v = (w < nwords) ? ((const unsigned int*)eiw)[w] : 0u;
        if (v) atomicOr(&iflag, 1);            // LDS atomic
    }
    __syncthreads();
    const bool is32 = (iflag != 0);

    const int base = (blockIdx.x * 256 + threadIdx.x) * 2;
    if (base >= E) return;

    int srcs[2], dsts[2];
    int ne;
    if ((E & 1) == 0 && base + 1 < E) {        // vector path (aligned: E even)
        ne = 2;
        if (is32) {                            // int32 layout: int2 loads
            int2 s = *(const int2*)(eiw + base);
            int2 d = *(const int2*)(eiw + E + base);
            srcs[0] = s.x; srcs[1] = s.y;
            dsts[0] = d.x; dsts[1] = d.y;
        } else {                               // int64 layout: int4, low words
            int4 sv = *(const int4*)(eiw + 2 * base);
            int4 dv = *(const int4*)(eiw + 2 * (E + base));
            srcs[0] = sv.x; srcs[1] = sv.z;
            dsts[0] = dv.x; dsts[1] = dv.z;
        }
    } else {                                   // scalar tail / odd shapes
        ne = 0;
        for (int e = base; e < E && e < base + 2; ++e, ++ne) {
            srcs[ne] = is32 ? eiw[e] : eiw[2 * e];
            dsts[ne] = is32 ? eiw[E + e] : eiw[2 * (E + e)];
        }
    }

#pragma unroll
    for (int j = 0; j < 2; ++j) {
        if (j >= ne) break;
        int dst = dsts[j];
        int pos = atomicAdd(&cnt[dst], 1);
        if (pos < CAP) {
            slots[(size_t)dst * CAP + pos] = srcs[j];
        } else {                               // essentially never
            int o = atomicAdd(ovfcnt, 1);
            ovf[2 * o]     = srcs[j];
            ovf[2 * o + 1] = dst;
        }
    }
}

// ---------------------------------------------------------------------------
// K2: fused atomic-free gather + projection. 256 threads, 64 nodes per block.
// __launch_bounds__(256,4): pins VGPR <= 128 -> >=4 blocks/CU (16 waves/CU);
// phase A is latency-bound on gathered U rows and lives on that TLP (R8's
// 8-accumulator phase B likely crossed the 128-VGPR cliff and regressed).
// Phase A: group g (16 lanes) owns node nd. Lane l covers edge-slot (l>>2)
//          and rank-quad (l&3): ONE global_load_dwordx4 per 4 edges per
//          group, 8-edge unroll -> 2 loads in flight. Partials combined by 2
//          shfl_xor rounds. Deterministic.
// Phase B: r-outer, blocked by 2 nodes: V fragment read once per k per PAIR
//          (192 LDS instr / 1536 B per thread vs R7's 256 / 2560 B) at only
//          ~+10 VGPR. accs reads are wave-broadcast b32 (conflict-free).
//          Nontemporal stores keep the 102 MB output stream from evicting
//          L2/L3-resident U and slots.
// Overflow fallback (deg > CAP) scans the tiny global list: correct for
// arbitrary inputs, never taken on random graphs.
// ---------------------------------------------------------------------------
__global__ __launch_bounds__(256, 4) void gather_project(
        const float* __restrict__ U,
        const float* __restrict__ V,
        const int* __restrict__ cnt,
        const int* __restrict__ slots,
        const int* __restrict__ ovfcnt,
        const int* __restrict__ ovf,
        float* __restrict__ out, int N) {
    __shared__ float4  Vs4[RANK * EMBED_DIM / 4];  // 8 KB
    __shared__ floatx4 accs4[64][4];               // 4 KB
    __shared__ float   sinv[64];
    __shared__ int     scnt[64];
    __shared__ int4    sslot4[64 * CAP / 4];       // 4 KB, flat/linear

    const int t = threadIdx.x;
    const float4* V4 = (const float4*)V;
    Vs4[t]       = V4[t];
    Vs4[t + 256] = V4[t + 256];

    const int n0 = blockIdx.x * 64;

    if (t < 64) {
        int n = n0 + t;
        int c = (n < N) ? cnt[n] : 0;
        scnt[t] = c;
        sinv[t] = 1.0f / fmaxf((float)c, 1.0f);
    }
    {   // 64 nodes x 16 ints = 256 int4, linear ds_write_b128
        const int4* g4 = (const int4*)(slots + (size_t)n0 * CAP);
        if (n0 + (t >> 2) < N) sslot4[t] = g4[t];
    }
    __syncthreads();

    const int* sslot = (const int*)sslot4;
    const int g    = t >> 4;   // node group 0..15
    const int l    = t & 15;   // lane in group
    const int es   = l >> 2;   // edge slot 0..3
    const int quad = l & 3;    // rank quad 0..3

#pragma unroll
    for (int half = 0; half < 4; ++half) {
        int nd = half * 16 + g;
        int n = n0 + nd;
        int deg = scnt[nd];
        int k = deg < CAP ? deg : CAP;
        const int* sl = sslot + nd * CAP;
        floatx4 a = (floatx4)0.f;
        for (int e = 0; e < k; e += 8) {
            // e < k inside loop => k >= 1 => clamped index valid; poison
            // slots beyond deg are never dereferenced.
            int e0 = e + es;
            int e1 = e + 4 + es;
            int i0 = e0 < k ? e0 : k - 1;
            int i1 = e1 < k ? e1 : k - 1;
            int s0 = sl[i0];
            int s1 = sl[i1];
            floatx4 u0 = *(const floatx4*)(U + (size_t)s0 * RANK + 4 * quad);
            floatx4 u1 = *(const floatx4*)(U + (size_t)s1 * RANK + 4 * quad);
            if (e0 < k) a += u0;
            if (e1 < k) a += u1;
        }
        // combine the 4 edge-slot partials (masks stay inside the 16-lane group)
        a += shflx4(a, 4);
        a += shflx4(a, 8);
        if (l < 4) {                            // lane l holds rank-quad l
            if (deg > CAP) {                    // correctness fallback
                int m = *ovfcnt;
                for (int i = 0; i < m; ++i)
                    if (ovf[2 * i + 1] == n)
                        a += *(const floatx4*)(U + (size_t)ovf[2 * i] * RANK + 4 * l);
            }
            accs4[nd][l] = a;
        }
    }
    __syncthreads();

    const float* accsf = (const float*)accs4;
    const int q = t & 31;   // float4 column
    const int w = t >> 5;   // node octet: nodes w*8 .. w*8+7

#pragma unroll
    for (int rp = 0; rp < 4; ++rp) {            // node pairs: 2 accumulators
        int nd0 = w * 8 + 2 * rp;
        floatx4 o0 = (floatx4)0.f, o1 = (floatx4)0.f;
#pragma unroll
        for (int k = 0; k < RANK; ++k) {
            float4 v = Vs4[k * 32 + q];         // one b128 per k per pair
            float a0 = accsf[nd0 * 16 + k];         // wave-broadcast b32
            float a1 = accsf[(nd0 + 1) * 16 + k];   // wave-broadcast b32
            o0.x = fmaf(a0, v.x, o0.x);
            o0.y = fmaf(a0, v.y, o0.y);
            o0.z = fmaf(a0, v.z, o0.z);
            o0.w = fmaf(a0, v.w, o0.w);
            o1.x = fmaf(a1, v.x, o1.x);
            o1.y = fmaf(a1, v.y, o1.y);
            o1.z = fmaf(a1, v.z, o1.z);
            o1.w = fmaf(a1, v.w, o1.w);
        }
        int na = n0 + nd0;
        if (na < N) {
            floatx4 oo = o0 * sinv[nd0];
            __builtin_nontemporal_store(
                oo, (floatx4*)out + (size_t)na * (EMBED_DIM / 4) + q);
        }
        if (na + 1 < N) {
            floatx4 oo = o1 * sinv[nd0 + 1];
            __builtin_nontemporal_store(
                oo, (floatx4*)out + (size_t)(na + 1) * (EMBED_DIM / 4) + q);
        }
    }
}

extern "C" void kernel_launch(void* const* d_in, const int* in_sizes, int n_in,
                              void* d_out, int out_size, void* d_ws, size_t ws_size,
                              hipStream_t stream) {
    const float* U = (const float*)d_in[0];
    const float* V = (const float*)d_in[1];
    const int* EI = (const int*)d_in[2];
    float* out = (float*)d_out;

    const int N = in_sizes[0] / RANK;   // 200000
    const int E = in_sizes[2] / 2;      // 640000
    const int nwords = in_sizes[2];     // >= word count under both layouts

    // workspace (int32): cnt[N] | ovfcnt[1] | pad | slots[N*CAP] | ovf[2E]
    int* wsI = (int*)d_ws;
    int* cnt = wsI;
    int* ovfcnt = wsI + N;
    const int slots_off = (N + 1 + 15) & ~15;   // 16B-align slots for int4
    int* slots = wsI + slots_off;
    int* ovf = slots + (size_t)N * CAP;

    // zero cnt + ovfcnt only (0.8 MB)
    (void)hipMemsetAsync(d_ws, 0, (size_t)(N + 1) * sizeof(int), stream);

    fill_slots<<<(E / 2 + 255) / 256, 256, 0, stream>>>(
        EI, cnt, ovfcnt, slots, ovf, E, nwords);

    gather_project<<<(N + 63) / 64, 256, 0, stream>>>(
        U, V, cnt, slots, ovfcnt, ovf, out, N);
}

// Round 10
// 171.651 us; speedup vs baseline: 1.1235x; 1.0550x over previous
//
#include <hip/hip_runtime.h>

#define RANK 16
#define EMBED_DIM 128
#define CAP 16   // slot capacity; Poisson(3.2) P(deg>16) ~ 1e-8/node.
                 // Overflow list keeps arbitrary inputs correct.

typedef float floatx4 __attribute__((ext_vector_type(4)));  // clang-native:
// __builtin_nontemporal_store accepts this (HIP float4 is a class, rejected).

__device__ inline floatx4 shflx4(floatx4 v, int mask) {
    floatx4 r;
    r.x = __shfl_xor(v.x, mask);
    r.y = __shfl_xor(v.y, mask);
    r.z = __shfl_xor(v.z, mask);
    r.w = __shfl_xor(v.w, mask);
    return r;
}

// ---------------------------------------------------------------------------
// K1: one pass over edges, 2 edges/thread (16B vector loads, 1250 blocks ->
// ~5 blocks/CU TLP to hide atomic+scattered-store latency). Per-block dtype
// detect (odd 32-bit words of int64 layout are high halves of node ids <
// 2^31 -> all zero; int32 layout -> random ids, surely nonzero among 256
// samples). Then:
//   pos = atomicAdd(cnt[dst]); pos < CAP ? slots[dst*CAP+pos] = src
//                                        : append (src,dst) to overflow list.
// ---------------------------------------------------------------------------
__global__ __launch_bounds__(256) void fill_slots(
        const int* __restrict__ eiw,   // edge_index as 32-bit words
        int* __restrict__ cnt,         // [N], pre-zeroed
        int* __restrict__ ovfcnt,      // [1], pre-zeroed
        int* __restrict__ slots,       // [N*CAP]
        int* __restrict__ ovf,         // [2*E]
        int E, int nwords) {
    __shared__ int iflag;
    if (threadIdx.x == 0) iflag = 0;
    __syncthreads();
    {
        int w = 2 * threadIdx.x + 1;
        unsigned int v = (w < nwords) ? ((const unsigned int*)eiw)[w] : 0u;
        if (v) atomicOr(&iflag, 1);            // LDS atomic
    }
    __syncthreads();
    const bool is32 = (iflag != 0);

    const int base = (blockIdx.x * 256 + threadIdx.x) * 2;
    if (base >= E) return;

    int srcs[2], dsts[2];
    int ne;
    if ((E & 1) == 0 && base + 1 < E) {        // vector path (aligned: E even)
        ne = 2;
        if (is32) {                            // int32 layout: int2 loads
            int2 s = *(const int2*)(eiw + base);
            int2 d = *(const int2*)(eiw + E + base);
            srcs[0] = s.x; srcs[1] = s.y;
            dsts[0] = d.x; dsts[1] = d.y;
        } else {                               // int64 layout: int4, low words
            int4 sv = *(const int4*)(eiw + 2 * base);
            int4 dv = *(const int4*)(eiw + 2 * (E + base));
            srcs[0] = sv.x; srcs[1] = sv.z;
            dsts[0] = dv.x; dsts[1] = dv.z;
        }
    } else {                                   // scalar tail / odd shapes
        ne = 0;
        for (int e = base; e < E && e < base + 2; ++e, ++ne) {
            srcs[ne] = is32 ? eiw[e] : eiw[2 * e];
            dsts[ne] = is32 ? eiw[E + e] : eiw[2 * (E + e)];
        }
    }

#pragma unroll
    for (int j = 0; j < 2; ++j) {
        if (j >= ne) break;
        int dst = dsts[j];
        int pos = atomicAdd(&cnt[dst], 1);
        if (pos < CAP) {
            slots[(size_t)dst * CAP + pos] = srcs[j];
        } else {                               // essentially never
            int o = atomicAdd(ovfcnt, 1);
            ovf[2 * o]     = srcs[j];
            ovf[2 * o + 1] = dst;
        }
    }
}

// ---------------------------------------------------------------------------
// K2: fused atomic-free gather + projection. 256 threads, 64 nodes per block
// (grid = ceil(N/64), one V/slot staging per block). Best-measured variant
// (R7, 174.8 us): r-outer phase B; pair-blocking (R9) and k-outer (R8) were
// neutral-to-negative -> phase B is not on the critical path.
// Phase A: group g (16 lanes) owns node nd. Lane l covers edge-slot (l>>2)
//          and rank-quad (l&3): ONE global_load_dwordx4 per 4 edges per
//          group, 8-edge unroll -> 2 loads in flight. Partials combined by 2
//          shfl_xor rounds (masks 4,8 — intra-group). Deterministic.
// Phase B: thread (q = t&31, w = t>>5) emits 8 nodes x float4 column of
//          (accs/deg) @ V with V LDS-cached; nontemporal stores keep the
//          102 MB output stream from evicting L2/L3-resident U and slots.
// Overflow fallback (deg > CAP) scans the tiny global list: correct for
// arbitrary inputs, never taken on random graphs.
// ---------------------------------------------------------------------------
__global__ __launch_bounds__(256) void gather_project(
        const float* __restrict__ U,
        const float* __restrict__ V,
        const int* __restrict__ cnt,
        const int* __restrict__ slots,
        const int* __restrict__ ovfcnt,
        const int* __restrict__ ovf,
        float* __restrict__ out, int N) {
    __shared__ float4  Vs4[RANK * EMBED_DIM / 4];  // 8 KB
    __shared__ floatx4 accs4[64][4];               // 4 KB
    __shared__ float   sinv[64];
    __shared__ int     scnt[64];
    __shared__ int4    sslot4[64 * CAP / 4];       // 4 KB, flat/linear

    const int t = threadIdx.x;
    const float4* V4 = (const float4*)V;
    Vs4[t]       = V4[t];
    Vs4[t + 256] = V4[t + 256];

    const int n0 = blockIdx.x * 64;

    if (t < 64) {
        int n = n0 + t;
        int c = (n < N) ? cnt[n] : 0;
        scnt[t] = c;
        sinv[t] = 1.0f / fmaxf((float)c, 1.0f);
    }
    {   // 64 nodes x 16 ints = 256 int4, linear ds_write_b128
        const int4* g4 = (const int4*)(slots + (size_t)n0 * CAP);
        if (n0 + (t >> 2) < N) sslot4[t] = g4[t];
    }
    __syncthreads();

    const int* sslot = (const int*)sslot4;
    const int g    = t >> 4;   // node group 0..15
    const int l    = t & 15;   // lane in group
    const int es   = l >> 2;   // edge slot 0..3
    const int quad = l & 3;    // rank quad 0..3

#pragma unroll
    for (int half = 0; half < 4; ++half) {
        int nd = half * 16 + g;
        int n = n0 + nd;
        int deg = scnt[nd];
        int k = deg < CAP ? deg : CAP;
        const int* sl = sslot + nd * CAP;
        floatx4 a = (floatx4)0.f;
        for (int e = 0; e < k; e += 8) {
            // e < k inside loop => k >= 1 => clamped index valid; poison
            // slots beyond deg are never dereferenced.
            int e0 = e + es;
            int e1 = e + 4 + es;
            int i0 = e0 < k ? e0 : k - 1;
            int i1 = e1 < k ? e1 : k - 1;
            int s0 = sl[i0];
            int s1 = sl[i1];
            floatx4 u0 = *(const floatx4*)(U + (size_t)s0 * RANK + 4 * quad);
            floatx4 u1 = *(const floatx4*)(U + (size_t)s1 * RANK + 4 * quad);
            if (e0 < k) a += u0;
            if (e1 < k) a += u1;
        }
        // combine the 4 edge-slot partials (masks stay inside the 16-lane group)
        a += shflx4(a, 4);
        a += shflx4(a, 8);
        if (l < 4) {                            // lane l holds rank-quad l
            if (deg > CAP) {                    // correctness fallback
                int m = *ovfcnt;
                for (int i = 0; i < m; ++i)
                    if (ovf[2 * i + 1] == n)
                        a += *(const floatx4*)(U + (size_t)ovf[2 * i] * RANK + 4 * l);
            }
            accs4[nd][l] = a;
        }
    }
    __syncthreads();

    const float* accsf = (const float*)accs4;
    const int q = t & 31;   // float4 column
    const int w = t >> 5;   // node octet
#pragma unroll
    for (int r = 0; r < 8; ++r) {
        int nd = w * 8 + r;
        floatx4 o = (floatx4)0.f;
#pragma unroll
        for (int k = 0; k < RANK; ++k) {
            float a = accsf[nd * 16 + k];       // 2-way broadcast: free
            float4 v = Vs4[k * 32 + q];
            o.x = fmaf(a, v.x, o.x);
            o.y = fmaf(a, v.y, o.y);
            o.z = fmaf(a, v.z, o.z);
            o.w = fmaf(a, v.w, o.w);
        }
        int n = n0 + nd;
        if (n < N) {
            o *= sinv[nd];
            __builtin_nontemporal_store(
                o, (floatx4*)out + (size_t)n * (EMBED_DIM / 4) + q);
        }
    }
}

extern "C" void kernel_launch(void* const* d_in, const int* in_sizes, int n_in,
                              void* d_out, int out_size, void* d_ws, size_t ws_size,
                              hipStream_t stream) {
    const float* U = (const float*)d_in[0];
    const float* V = (const float*)d_in[1];
    const int* EI = (const int*)d_in[2];
    float* out = (float*)d_out;

    const int N = in_sizes[0] / RANK;   // 200000
    const int E = in_sizes[2] / 2;      // 640000
    const int nwords = in_sizes[2];     // >= word count under both layouts

    // workspace (int32): cnt[N] | ovfcnt[1] | pad | slots[N*CAP] | ovf[2E]
    int* wsI = (int*)d_ws;
    int* cnt = wsI;
    int* ovfcnt = wsI + N;
    const int slots_off = (N + 1 + 15) & ~15;   // 16B-align slots for int4
    int* slots = wsI + slots_off;
    int* ovf = slots + (size_t)N * CAP;

    // zero cnt + ovfcnt only (0.8 MB)
    (void)hipMemsetAsync(d_ws, 0, (size_t)(N + 1) * sizeof(int), stream);

    fill_slots<<<(E / 2 + 255) / 256, 256, 0, stream>>>(
        EI, cnt, ovfcnt, slots, ovf, E, nwords);

    gather_project<<<(N + 63) / 64, 256, 0, stream>>>(
        U, V, cnt, slots, ovfcnt, ovf, out, N);
}